// Round 3
// baseline (1620.780 us; speedup 1.0000x reference)
//
#include <hip/hip_runtime.h>
#include <hip/hip_bf16.h>

#define N_USERS 100000
#define N_ITEMS 50000
#define NNZ_EDGES 1600000
#define DIM 64

#define BD 128                               // destinations per bucket
#define BSHIFT 7
#define NBU ((N_USERS + BD - 1) / BD)        // 782
#define NBI ((N_ITEMS + BD - 1) / BD)        // 391
#define NB_MAX NBU
#define TILE 4096                            // edges per binning tile

// ---------------------------------------------------------------------------
// Dense GEMM: Y[nrows,64] = X[nrows,64] @ W[64,64]. W staged in LDS.
// ---------------------------------------------------------------------------
__global__ __launch_bounds__(256) void gemm64_kernel(
    const float* __restrict__ X, const float* __restrict__ W,
    float* __restrict__ Y, int nrows) {
  __shared__ float sW[64][64];
  __shared__ float sX[4][64];
  const int tid = threadIdx.x;

  #pragma unroll
  for (int i = 0; i < 16; ++i) {
    int idx = tid + i * 256;
    sW[idx >> 6][idx & 63] = W[idx];
  }

  const int r = tid >> 6;
  const int c = tid & 63;
  const int row = blockIdx.x * 4 + r;
  if (row < nrows) sX[r][c] = X[row * DIM + c];
  __syncthreads();

  if (row < nrows) {
    float acc = 0.f;
    #pragma unroll
    for (int k = 0; k < DIM; ++k) acc = fmaf(sX[r][k], sW[k][c], acc);
    Y[row * DIM + c] = acc;
  }
}

// ---------------------------------------------------------------------------
// Coarse bucket histogram for both directions. LDS hist per block, one
// global atomicAdd per (block, nonzero bucket).
// ---------------------------------------------------------------------------
__global__ __launch_bounds__(256) void bucket_hist_kernel(
    const int* __restrict__ rows, const int* __restrict__ cols,
    int* __restrict__ ucnt, int* __restrict__ icnt, int nnz) {
  __shared__ int hu[NBU];
  __shared__ int hi_[NBI];
  for (int j = threadIdx.x; j < NBU; j += 256) hu[j] = 0;
  for (int j = threadIdx.x; j < NBI; j += 256) hi_[j] = 0;
  __syncthreads();
  for (int i = blockIdx.x * 256 + threadIdx.x; i < nnz; i += gridDim.x * 256) {
    atomicAdd(&hu[rows[i] >> BSHIFT], 1);
    atomicAdd(&hi_[cols[i] >> BSHIFT], 1);
  }
  __syncthreads();
  for (int j = threadIdx.x; j < NBU; j += 256) if (hu[j]) atomicAdd(&ucnt[j], hu[j]);
  for (int j = threadIdx.x; j < NBI; j += 256) if (hi_[j]) atomicAdd(&icnt[j], hi_[j]);
}

// ---------------------------------------------------------------------------
// Exclusive scan of bucket counts (n <= 1024, single chunk). Block 0 = user,
// block 1 = item. Writes off[0..n] and initializes cur = off.
// ---------------------------------------------------------------------------
__global__ __launch_bounds__(1024) void coarse_scan_kernel(
    int* __restrict__ ucnt, int* __restrict__ uoff, int* __restrict__ ucur,
    int* __restrict__ icnt, int* __restrict__ ioff, int* __restrict__ icur) {
  __shared__ int s_w[16];
  int* cnt; int* off; int* cur; int n;
  if (blockIdx.x == 0) { cnt = ucnt; off = uoff; cur = ucur; n = NBU; }
  else                 { cnt = icnt; off = ioff; cur = icur; n = NBI; }
  const int tid = threadIdx.x, lane = tid & 63, wid = tid >> 6;
  const int x = (tid < n) ? cnt[tid] : 0;
  int incl = x;
  #pragma unroll
  for (int d = 1; d < 64; d <<= 1) {
    int t = __shfl_up(incl, d);
    if (lane >= d) incl += t;
  }
  if (lane == 63) s_w[wid] = incl;
  __syncthreads();
  if (wid == 0) {
    int y = (lane < 16) ? s_w[lane] : 0;
    #pragma unroll
    for (int d = 1; d < 16; d <<= 1) {
      int t = __shfl_up(y, d);
      if (lane >= d) y += t;
    }
    if (lane < 16) s_w[lane] = y;
  }
  __syncthreads();
  const int base = (wid == 0) ? 0 : s_w[wid - 1];
  const int excl = base + incl - x;
  if (tid < n) { off[tid] = excl; cur[tid] = excl; }
  if (tid == 0) off[n] = s_w[15];
}

// ---------------------------------------------------------------------------
// LDS-binning: group edges by coarse destination bucket. Per 4096-edge tile:
// LDS histogram -> LDS scan -> LDS reorder -> per-bucket global reservation ->
// contiguous-run writeout. Record = (dst_local<<17 | src, val_bits), 8B.
// ---------------------------------------------------------------------------
__global__ __launch_bounds__(256) void binning_kernel(
    const int* __restrict__ keys, const int* __restrict__ srcs,
    const float* __restrict__ vals, int* __restrict__ cb_cur,
    uint2* __restrict__ out, int nnz, int nb) {
  __shared__ int sh[NB_MAX];          // hist -> excl -> running cursor
  __shared__ int scnt[NB_MAX];        // counts -> excl (recovered)
  __shared__ int sg[NB_MAX];          // global base per bucket (this tile)
  __shared__ uint2 sbuf[TILE];        // reordered records
  __shared__ unsigned short sbk[TILE];// bucket of each record
  __shared__ int s_w[8];

  const int tid = threadIdx.x, lane = tid & 63, wid = tid >> 6;
  const int tbase = blockIdx.x * TILE;
  const int total = min(TILE, nnz - tbase);

  for (int j = tid; j < nb; j += 256) sh[j] = 0;
  __syncthreads();

  // load + LDS histogram; stash records in registers (static indices).
  int bk[16]; unsigned pk[16]; unsigned vv[16];
  #pragma unroll
  for (int k = 0; k < 16; ++k) {
    const int i = tbase + k * 256 + tid;
    if (i < nnz) {
      const int key = keys[i];
      const int b = key >> BSHIFT;
      bk[k] = b;
      pk[k] = ((unsigned)(key & (BD - 1)) << 17) | (unsigned)srcs[i];
      vv[k] = __float_as_uint(vals[i]);
      atomicAdd(&sh[b], 1);
    } else {
      bk[k] = -1; pk[k] = 0; vv[k] = 0;
    }
  }
  __syncthreads();

  // exclusive scan of sh[0..nb); keep counts in scnt.
  int carry = 0;
  for (int cb = 0; cb < nb; cb += 256) {
    const int idx = cb + tid;
    const int x = (idx < nb) ? sh[idx] : 0;
    int incl = x;
    #pragma unroll
    for (int d = 1; d < 64; d <<= 1) {
      int t = __shfl_up(incl, d);
      if (lane >= d) incl += t;
    }
    if (lane == 63) s_w[wid] = incl;
    __syncthreads();
    if (tid == 0) {
      int a = 0;
      #pragma unroll
      for (int w = 0; w < 4; ++w) { const int t = s_w[w]; s_w[w] = a; a += t; }
      s_w[4] = a;
    }
    __syncthreads();
    const int excl = carry + s_w[wid] + incl - x;
    if (idx < nb) { scnt[idx] = x; sh[idx] = excl; }
    carry += s_w[4];
    __syncthreads();
  }

  // place records into LDS at bucket-local positions.
  #pragma unroll
  for (int k = 0; k < 16; ++k) {
    if (bk[k] >= 0) {
      const int p = atomicAdd(&sh[bk[k]], 1);
      sbuf[p] = make_uint2(pk[k], vv[k]);
      sbk[p] = (unsigned short)bk[k];
    }
  }
  __syncthreads();

  // reserve global space per bucket; recover excl into scnt.
  for (int b = tid; b < nb; b += 256) {
    const int c = scnt[b];
    if (c > 0) sg[b] = atomicAdd(&cb_cur[b], c);
    scnt[b] = sh[b] - c;  // = excl[b]
  }
  __syncthreads();

  // contiguous-run writeout.
  for (int p = tid; p < total; p += 256) {
    const int b = sbk[p];
    out[sg[b] + (p - scnt[b])] = sbuf[p];
  }
}

// ---------------------------------------------------------------------------
// Bucket SpMM + fused ReLU. One block per bucket; 128x64 f32 accumulator in
// LDS; edges broadcast via shfl; per-edge LDS float atomicAdd (ds_add_f32,
// 64 consecutive addresses -> conflict-free). Single coalesced writeout.
// ---------------------------------------------------------------------------
__global__ __launch_bounds__(256) void spmm_bucket_kernel(
    const uint2* __restrict__ edges, const int* __restrict__ cb_off,
    const float* __restrict__ xw, float* __restrict__ out, int ndst) {
  __shared__ float acc[BD * DIM];  // 32 KB
  const int tid = threadIdx.x, lane = tid & 63, wid = tid >> 6;
  const int b = blockIdx.x;

  for (int j = tid; j < BD * DIM; j += 256) acc[j] = 0.f;
  __syncthreads();

  const int beg = cb_off[b], end = cb_off[b + 1];
  for (int k = beg + wid * 64; k < end; k += 256) {
    const int nbt = min(64, end - k);
    int pr = 0, vr = 0;
    if (lane < nbt) {
      const uint2 e = edges[k + lane];
      pr = (int)e.x; vr = (int)e.y;
    }
    for (int j = 0; j < nbt; ++j) {
      const unsigned pack = (unsigned)__shfl(pr, j);
      const float v = __uint_as_float((unsigned)__shfl(vr, j));
      const int dl = (int)(pack >> 17);
      const int src = (int)(pack & 0x1FFFFu);
      atomicAdd(&acc[dl * DIM + lane], v * xw[(size_t)src * DIM + lane]);
    }
  }
  __syncthreads();

  const int nrows = min(BD, ndst - b * BD);
  const int nout = nrows * DIM;
  float* obase = out + (size_t)b * BD * DIM;
  for (int j = tid; j < nout; j += 256) obase[j] = fmaxf(acc[j], 0.f);
}

extern "C" void kernel_launch(void* const* d_in, const int* in_sizes, int n_in,
                              void* d_out, int out_size, void* d_ws, size_t ws_size,
                              hipStream_t stream) {
  const float* user_x      = (const float*)d_in[0];
  const float* item_x      = (const float*)d_in[1];
  const float* user_weight = (const float*)d_in[2];
  const float* item_weight = (const float*)d_in[3];
  const int*   ui_rows     = (const int*)d_in[4];
  const int*   ui_cols     = (const int*)d_in[5];
  const float* ui_vals     = (const float*)d_in[6];

  float* out_user = (float*)d_out;
  float* out_item = (float*)d_out + (size_t)N_USERS * DIM;

  // ---- workspace layout (4-byte words; all segments 8B-aligned) ----------
  float* xw_user  = (float*)d_ws;                       // 6,400,000
  float* xw_item  = xw_user + (size_t)N_USERS * DIM;    // 3,200,000
  uint2* binned_u = (uint2*)(xw_item + (size_t)N_ITEMS * DIM); // NNZ uint2
  uint2* binned_i = binned_u + NNZ_EDGES;               // NNZ uint2
  int*   cbu_cnt  = (int*)(binned_i + NNZ_EDGES);       // NBU
  int*   cbi_cnt  = cbu_cnt + NBU;                      // NBI (contig for memset)
  int*   cbu_off  = cbi_cnt + NBI;                      // NBU+1
  int*   cbi_off  = cbu_off + (NBU + 1);                // NBI+1
  int*   cbu_cur  = cbi_off + (NBI + 1);                // NBU
  int*   cbi_cur  = cbu_cur + NBU;                      // NBI
  // total ~64.1 MB

  // Dense projections.
  gemm64_kernel<<<(N_USERS + 3) / 4, 256, 0, stream>>>(user_x, user_weight, xw_user, N_USERS);
  gemm64_kernel<<<(N_ITEMS + 3) / 4, 256, 0, stream>>>(item_x, item_weight, xw_item, N_ITEMS);

  // Coarse bucket counts -> offsets/cursors.
  hipMemsetAsync(cbu_cnt, 0, (NBU + NBI) * sizeof(int), stream);
  bucket_hist_kernel<<<256, 256, 0, stream>>>(ui_rows, ui_cols, cbu_cnt, cbi_cnt, NNZ_EDGES);
  coarse_scan_kernel<<<2, 1024, 0, stream>>>(cbu_cnt, cbu_off, cbu_cur,
                                             cbi_cnt, cbi_off, cbi_cur);

  // Bin edges by coarse destination bucket (both directions).
  const int nblk = (NNZ_EDGES + TILE - 1) / TILE;
  binning_kernel<<<nblk, 256, 0, stream>>>(ui_rows, ui_cols, ui_vals, cbu_cur,
                                           binned_u, NNZ_EDGES, NBU);
  binning_kernel<<<nblk, 256, 0, stream>>>(ui_cols, ui_rows, ui_vals, cbi_cur,
                                           binned_i, NNZ_EDGES, NBI);

  // Bucket SpMM + fused ReLU.
  spmm_bucket_kernel<<<NBU, 256, 0, stream>>>(binned_u, cbu_off, xw_item, out_user, N_USERS);
  spmm_bucket_kernel<<<NBI, 256, 0, stream>>>(binned_i, cbi_off, xw_user, out_item, N_ITEMS);
}

// Round 4
// 1438.031 us; speedup vs baseline: 1.1271x; 1.1271x over previous
//
#include <hip/hip_runtime.h>
#include <hip/hip_bf16.h>

#define N_USERS 100000
#define N_ITEMS 50000
#define NNZ_EDGES 1600000
#define DIM 64

#define BD 64                                // destinations per bucket
#define BSHIFT 6
#define NBU ((N_USERS + BD - 1) / BD)        // 1563
#define NBI ((N_ITEMS + BD - 1) / BD)        // 782
#define NB_MAX NBU
#define TILE 4096                            // edges per binning tile

__device__ inline unsigned short f32_to_bf16(float f) {
  unsigned u = __float_as_uint(f);
  unsigned r = (u + 0x7FFFu + ((u >> 16) & 1u)) >> 16;  // RNE
  return (unsigned short)r;
}

// ---------------------------------------------------------------------------
// Dense GEMM: Y[nrows,64] = bf16(X[nrows,64] @ W[64,64]). W staged in LDS.
// ---------------------------------------------------------------------------
__global__ __launch_bounds__(256) void gemm64_bf16_kernel(
    const float* __restrict__ X, const float* __restrict__ W,
    unsigned short* __restrict__ Y, int nrows) {
  __shared__ float sW[64][64];
  __shared__ float sX[4][64];
  const int tid = threadIdx.x;

  #pragma unroll
  for (int i = 0; i < 16; ++i) {
    int idx = tid + i * 256;
    sW[idx >> 6][idx & 63] = W[idx];
  }

  const int r = tid >> 6;
  const int c = tid & 63;
  const int row = blockIdx.x * 4 + r;
  if (row < nrows) sX[r][c] = X[row * DIM + c];
  __syncthreads();

  if (row < nrows) {
    float acc = 0.f;
    #pragma unroll
    for (int k = 0; k < DIM; ++k) acc = fmaf(sX[r][k], sW[k][c], acc);
    Y[row * DIM + c] = f32_to_bf16(acc);
  }
}

// ---------------------------------------------------------------------------
// Coarse bucket histogram for both directions (LDS hist per block).
// ---------------------------------------------------------------------------
__global__ __launch_bounds__(256) void bucket_hist_kernel(
    const int* __restrict__ rows, const int* __restrict__ cols,
    int* __restrict__ ucnt, int* __restrict__ icnt, int nnz) {
  __shared__ int hu[NBU];
  __shared__ int hi_[NBI];
  for (int j = threadIdx.x; j < NBU; j += 256) hu[j] = 0;
  for (int j = threadIdx.x; j < NBI; j += 256) hi_[j] = 0;
  __syncthreads();
  for (int i = blockIdx.x * 256 + threadIdx.x; i < nnz; i += gridDim.x * 256) {
    atomicAdd(&hu[rows[i] >> BSHIFT], 1);
    atomicAdd(&hi_[cols[i] >> BSHIFT], 1);
  }
  __syncthreads();
  for (int j = threadIdx.x; j < NBU; j += 256) if (hu[j]) atomicAdd(&ucnt[j], hu[j]);
  for (int j = threadIdx.x; j < NBI; j += 256) if (hi_[j]) atomicAdd(&icnt[j], hi_[j]);
}

// ---------------------------------------------------------------------------
// Exclusive scan of bucket counts (chunked, n up to 1563). Block 0 = user,
// block 1 = item. Writes off[0..n], initializes cur = off.
// ---------------------------------------------------------------------------
__global__ __launch_bounds__(1024) void coarse_scan_kernel(
    int* __restrict__ ucnt, int* __restrict__ uoff, int* __restrict__ ucur,
    int* __restrict__ icnt, int* __restrict__ ioff, int* __restrict__ icur) {
  __shared__ int s_w[16];
  int *cnt, *off, *cur; int n;
  if (blockIdx.x == 0) { cnt = ucnt; off = uoff; cur = ucur; n = NBU; }
  else                 { cnt = icnt; off = ioff; cur = icur; n = NBI; }
  const int tid = threadIdx.x, lane = tid & 63, wid = tid >> 6;

  int running = 0;
  for (int base = 0; base < n; base += 1024) {
    const int i = base + tid;
    const int x = (i < n) ? cnt[i] : 0;
    int incl = x;
    #pragma unroll
    for (int d = 1; d < 64; d <<= 1) {
      int t = __shfl_up(incl, d);
      if (lane >= d) incl += t;
    }
    if (lane == 63) s_w[wid] = incl;
    __syncthreads();
    if (wid == 0) {
      int y = (lane < 16) ? s_w[lane] : 0;
      #pragma unroll
      for (int d = 1; d < 16; d <<= 1) {
        int t = __shfl_up(y, d);
        if (lane >= d) y += t;
      }
      if (lane < 16) s_w[lane] = y;
    }
    __syncthreads();
    const int wb = (wid == 0) ? 0 : s_w[wid - 1];
    const int excl = running + wb + incl - x;
    if (i < n) { off[i] = excl; cur[i] = excl; }
    const int tot = s_w[15];
    __syncthreads();
    running += tot;
  }
  if (tid == 0) off[n] = running;
}

// ---------------------------------------------------------------------------
// LDS-binning: group edges by coarse destination bucket. Per 4096-edge tile:
// LDS hist -> LDS scan -> LDS reorder -> per-bucket global reservation ->
// contiguous-run writeout. Record = (dst_local<<17 | src, val_bits), 8B.
// ---------------------------------------------------------------------------
__global__ __launch_bounds__(256) void binning_kernel(
    const int* __restrict__ keys, const int* __restrict__ srcs,
    const float* __restrict__ vals, int* __restrict__ cb_cur,
    uint2* __restrict__ out, int nnz, int nb) {
  __shared__ int sh[NB_MAX];          // hist -> excl -> running cursor
  __shared__ int scnt[NB_MAX];        // counts -> excl (recovered)
  __shared__ int sg[NB_MAX];          // global base per bucket (this tile)
  __shared__ uint2 sbuf[TILE];        // reordered records
  __shared__ unsigned short sbk[TILE];// bucket of each record
  __shared__ int s_w[8];

  const int tid = threadIdx.x, lane = tid & 63, wid = tid >> 6;
  const int tbase = blockIdx.x * TILE;
  const int total = min(TILE, nnz - tbase);

  for (int j = tid; j < nb; j += 256) sh[j] = 0;
  __syncthreads();

  int bk[16]; unsigned pk[16]; unsigned vv[16];
  #pragma unroll
  for (int k = 0; k < 16; ++k) {
    const int i = tbase + k * 256 + tid;
    if (i < nnz) {
      const int key = keys[i];
      const int b = key >> BSHIFT;
      bk[k] = b;
      pk[k] = ((unsigned)(key & (BD - 1)) << 17) | (unsigned)srcs[i];
      vv[k] = __float_as_uint(vals[i]);
      atomicAdd(&sh[b], 1);
    } else {
      bk[k] = -1; pk[k] = 0; vv[k] = 0;
    }
  }
  __syncthreads();

  // exclusive scan of sh[0..nb); counts kept in scnt.
  int carry = 0;
  for (int cb = 0; cb < nb; cb += 256) {
    const int idx = cb + tid;
    const int x = (idx < nb) ? sh[idx] : 0;
    int incl = x;
    #pragma unroll
    for (int d = 1; d < 64; d <<= 1) {
      int t = __shfl_up(incl, d);
      if (lane >= d) incl += t;
    }
    if (lane == 63) s_w[wid] = incl;
    __syncthreads();
    if (tid == 0) {
      int a = 0;
      #pragma unroll
      for (int w = 0; w < 4; ++w) { const int t = s_w[w]; s_w[w] = a; a += t; }
      s_w[4] = a;
    }
    __syncthreads();
    const int excl = carry + s_w[wid] + incl - x;
    if (idx < nb) { scnt[idx] = x; sh[idx] = excl; }
    carry += s_w[4];
    __syncthreads();
  }

  // place records into LDS at bucket-local positions.
  #pragma unroll
  for (int k = 0; k < 16; ++k) {
    if (bk[k] >= 0) {
      const int p = atomicAdd(&sh[bk[k]], 1);
      sbuf[p] = make_uint2(pk[k], vv[k]);
      sbk[p] = (unsigned short)bk[k];
    }
  }
  __syncthreads();

  // reserve global space per bucket; recover excl into scnt.
  for (int b = tid; b < nb; b += 256) {
    const int c = scnt[b];
    if (c > 0) sg[b] = atomicAdd(&cb_cur[b], c);
    scnt[b] = sh[b] - c;  // = excl[b]
  }
  __syncthreads();

  // contiguous-run writeout.
  for (int p = tid; p < total; p += 256) {
    const int b = sbk[p];
    out[sg[b] + (p - scnt[b])] = sbuf[p];
  }
}

// ---------------------------------------------------------------------------
// Bucket SpMM + fused ReLU. One block per 64-dest bucket. 16 threads/edge
// (lane = 4-feature chunk) -> 16 independent gathers in flight per wave,
// plus 1-deep prefetch of next record + gather. bf16 xw halves gather bytes.
// LDS acc padded to 65 f32/row, feature-interleaved: f at [dl*65+(f&3)*16+(f>>2)].
// ---------------------------------------------------------------------------
__global__ __launch_bounds__(256) void spmm_bucket_kernel(
    const uint2* __restrict__ edges, const int* __restrict__ off,
    const unsigned short* __restrict__ xw, float* __restrict__ out, int ndst) {
  __shared__ float acc[BD * 65];  // 16.6 KB
  const int tid = threadIdx.x;
  const int grp = tid >> 4;       // edge slot 0..15
  const int chunk = tid & 15;     // feature chunk (4 bf16 = 8B)
  const int b = blockIdx.x;

  for (int j = tid; j < BD * 65; j += 256) acc[j] = 0.f;
  __syncthreads();

  const int beg = off[b], end = off[b + 1];

  int e = beg + grp;
  uint2 rec = (e < end) ? edges[e] : make_uint2(0u, 0u);
  uint2 g = ((const uint2*)(xw + ((size_t)(rec.x & 0x1FFFFu) << 6)))[chunk];

  while (true) {
    const int en = e + 16;
    uint2 rec_n = make_uint2(0u, 0u);
    if (en < end) rec_n = edges[en];
    const uint2 g_n = ((const uint2*)(xw + ((size_t)(rec_n.x & 0x1FFFFu) << 6)))[chunk];

    const float v = __uint_as_float(rec.y);
    const int dl = (int)(rec.x >> 17);
    float* a = acc + dl * 65 + chunk;
    atomicAdd(a +  0, v * __uint_as_float(g.x << 16));
    atomicAdd(a + 16, v * __uint_as_float(g.x & 0xFFFF0000u));
    atomicAdd(a + 32, v * __uint_as_float(g.y << 16));
    atomicAdd(a + 48, v * __uint_as_float(g.y & 0xFFFF0000u));

    if (en >= end) break;
    rec = rec_n; g = g_n; e = en;
  }
  __syncthreads();

  const int base_row = b * BD;
  const int nrows = min(BD, ndst - base_row);
  const int nout = nrows * DIM;
  for (int idx = tid; idx < nout; idx += 256) {
    const int row = idx >> 6, f = idx & 63;
    out[(size_t)(base_row + row) * DIM + f] =
        fmaxf(acc[row * 65 + (f & 3) * 16 + (f >> 2)], 0.f);
  }
}

extern "C" void kernel_launch(void* const* d_in, const int* in_sizes, int n_in,
                              void* d_out, int out_size, void* d_ws, size_t ws_size,
                              hipStream_t stream) {
  const float* user_x      = (const float*)d_in[0];
  const float* item_x      = (const float*)d_in[1];
  const float* user_weight = (const float*)d_in[2];
  const float* item_weight = (const float*)d_in[3];
  const int*   ui_rows     = (const int*)d_in[4];
  const int*   ui_cols     = (const int*)d_in[5];
  const float* ui_vals     = (const float*)d_in[6];

  float* out_user = (float*)d_out;
  float* out_item = (float*)d_out + (size_t)N_USERS * DIM;

  // ---- workspace layout --------------------------------------------------
  unsigned short* xw_user = (unsigned short*)d_ws;               // 6.4M bf16
  unsigned short* xw_item = xw_user + (size_t)N_USERS * DIM;     // 3.2M bf16
  uint2* binned_u = (uint2*)(xw_item + (size_t)N_ITEMS * DIM);   // NNZ uint2
  uint2* binned_i = binned_u + NNZ_EDGES;                        // NNZ uint2
  int*   cbu_cnt  = (int*)(binned_i + NNZ_EDGES);                // NBU
  int*   cbi_cnt  = cbu_cnt + NBU;                               // NBI
  int*   cbu_off  = cbi_cnt + NBI;                               // NBU+1
  int*   cbi_off  = cbu_off + (NBU + 1);                         // NBI+1
  int*   cbu_cur  = cbi_off + (NBI + 1);                         // NBU
  int*   cbi_cur  = cbu_cur + NBU;                               // NBI
  // total ~44.8 MB

  // Dense projections (bf16 output for the gather phase).
  gemm64_bf16_kernel<<<(N_USERS + 3) / 4, 256, 0, stream>>>(user_x, user_weight, xw_user, N_USERS);
  gemm64_bf16_kernel<<<(N_ITEMS + 3) / 4, 256, 0, stream>>>(item_x, item_weight, xw_item, N_ITEMS);

  // Coarse bucket counts -> offsets/cursors.
  hipMemsetAsync(cbu_cnt, 0, (NBU + NBI) * sizeof(int), stream);
  bucket_hist_kernel<<<256, 256, 0, stream>>>(ui_rows, ui_cols, cbu_cnt, cbi_cnt, NNZ_EDGES);
  coarse_scan_kernel<<<2, 1024, 0, stream>>>(cbu_cnt, cbu_off, cbu_cur,
                                             cbi_cnt, cbi_off, cbi_cur);

  // Bin edges by coarse destination bucket (both directions).
  const int nblk = (NNZ_EDGES + TILE - 1) / TILE;
  binning_kernel<<<nblk, 256, 0, stream>>>(ui_rows, ui_cols, ui_vals, cbu_cur,
                                           binned_u, NNZ_EDGES, NBU);
  binning_kernel<<<nblk, 256, 0, stream>>>(ui_cols, ui_rows, ui_vals, cbi_cur,
                                           binned_i, NNZ_EDGES, NBI);

  // Bucket SpMM + fused ReLU (direct store, no output atomics, no memset).
  spmm_bucket_kernel<<<NBU, 256, 0, stream>>>(binned_u, cbu_off, xw_item, out_user, N_USERS);
  spmm_bucket_kernel<<<NBI, 256, 0, stream>>>(binned_i, cbi_off, xw_user, out_item, N_ITEMS);
}

// Round 5
// 328.727 us; speedup vs baseline: 4.9305x; 4.3745x over previous
//
#include <hip/hip_runtime.h>
#include <hip/hip_bf16.h>

#define N_USERS 100000
#define N_ITEMS 50000
#define NNZ_EDGES 1600000
#define DIM 64

#define BSHIFT_U 6
#define BD_U 64                              // user dests per coarse bucket
#define BSHIFT_I 5
#define BD_I 32                              // item dests per coarse bucket
#define NBU ((N_USERS + BD_U - 1) / BD_U)    // 1563
#define NBI ((N_ITEMS + BD_I - 1) / BD_I)    // 1563
#define NB_MAX 1563
#define TILE 4096                            // edges per binning tile

__device__ inline unsigned short f32_to_bf16(float f) {
  unsigned u = __float_as_uint(f);
  unsigned r = (u + 0x7FFFu + ((u >> 16) & 1u)) >> 16;  // RNE
  return (unsigned short)r;
}
__device__ inline float bf16_to_f32(unsigned short h) {
  return __uint_as_float((unsigned)h << 16);
}

// ---------------------------------------------------------------------------
// Dense GEMM: Y[nrows,64] = bf16(X @ W). 16 rows/block, thread = (r0,c) with
// 4 outputs (rows r0+4i). W (16KB) + 16 X rows (4KB) in LDS.
// ---------------------------------------------------------------------------
__global__ __launch_bounds__(256) void gemm64_bf16_kernel(
    const float* __restrict__ X, const float* __restrict__ W,
    unsigned short* __restrict__ Y, int nrows) {
  __shared__ float sW[64][64];
  __shared__ float sX[16][64];
  const int tid = threadIdx.x;

  #pragma unroll
  for (int i = 0; i < 16; ++i) {
    int idx = tid + i * 256;
    sW[idx >> 6][idx & 63] = W[idx];
  }

  const int r0 = tid >> 6;       // 0..3
  const int c  = tid & 63;
  const int row_base = blockIdx.x * 16;
  #pragma unroll
  for (int i = 0; i < 4; ++i) {
    const int rr = r0 + i * 4;
    const int row = row_base + rr;
    sX[rr][c] = (row < nrows) ? X[(size_t)row * DIM + c] : 0.f;
  }
  __syncthreads();

  float a0 = 0.f, a1 = 0.f, a2 = 0.f, a3 = 0.f;
  #pragma unroll
  for (int k = 0; k < DIM; ++k) {
    const float w = sW[k][c];
    a0 = fmaf(sX[r0][k],      w, a0);
    a1 = fmaf(sX[r0 + 4][k],  w, a1);
    a2 = fmaf(sX[r0 + 8][k],  w, a2);
    a3 = fmaf(sX[r0 + 12][k], w, a3);
  }
  int row = row_base + r0;
  if (row < nrows) Y[(size_t)row * DIM + c] = f32_to_bf16(a0);
  row += 4;  if (row < nrows) Y[(size_t)row * DIM + c] = f32_to_bf16(a1);
  row += 4;  if (row < nrows) Y[(size_t)row * DIM + c] = f32_to_bf16(a2);
  row += 4;  if (row < nrows) Y[(size_t)row * DIM + c] = f32_to_bf16(a3);
}

// ---------------------------------------------------------------------------
// Coarse bucket histogram, both directions (LDS int hist per block).
// ---------------------------------------------------------------------------
__global__ __launch_bounds__(256) void bucket_hist_kernel(
    const int* __restrict__ rows, const int* __restrict__ cols,
    int* __restrict__ ucnt, int* __restrict__ icnt, int nnz) {
  __shared__ int hu[NBU];
  __shared__ int hi_[NBI];
  for (int j = threadIdx.x; j < NBU; j += 256) hu[j] = 0;
  for (int j = threadIdx.x; j < NBI; j += 256) hi_[j] = 0;
  __syncthreads();
  for (int i = blockIdx.x * 256 + threadIdx.x; i < nnz; i += gridDim.x * 256) {
    atomicAdd(&hu[rows[i] >> BSHIFT_U], 1);
    atomicAdd(&hi_[cols[i] >> BSHIFT_I], 1);
  }
  __syncthreads();
  for (int j = threadIdx.x; j < NBU; j += 256) if (hu[j]) atomicAdd(&ucnt[j], hu[j]);
  for (int j = threadIdx.x; j < NBI; j += 256) if (hi_[j]) atomicAdd(&icnt[j], hi_[j]);
}

// ---------------------------------------------------------------------------
// Exclusive scan of bucket counts (n up to 1563, chunked by 1024).
// Block 0 = user, block 1 = item. Writes off[0..n], initializes cur = off.
// ---------------------------------------------------------------------------
__global__ __launch_bounds__(1024) void coarse_scan_kernel(
    int* __restrict__ ucnt, int* __restrict__ uoff, int* __restrict__ ucur,
    int* __restrict__ icnt, int* __restrict__ ioff, int* __restrict__ icur) {
  __shared__ int s_w[16];
  int *cnt, *off, *cur; int n;
  if (blockIdx.x == 0) { cnt = ucnt; off = uoff; cur = ucur; n = NBU; }
  else                 { cnt = icnt; off = ioff; cur = icur; n = NBI; }
  const int tid = threadIdx.x, lane = tid & 63, wid = tid >> 6;

  int running = 0;
  for (int base = 0; base < n; base += 1024) {
    const int i = base + tid;
    const int x = (i < n) ? cnt[i] : 0;
    int incl = x;
    #pragma unroll
    for (int d = 1; d < 64; d <<= 1) {
      int t = __shfl_up(incl, d);
      if (lane >= d) incl += t;
    }
    if (lane == 63) s_w[wid] = incl;
    __syncthreads();
    if (wid == 0) {
      int y = (lane < 16) ? s_w[lane] : 0;
      #pragma unroll
      for (int d = 1; d < 16; d <<= 1) {
        int t = __shfl_up(y, d);
        if (lane >= d) y += t;
      }
      if (lane < 16) s_w[lane] = y;
    }
    __syncthreads();
    const int wb = (wid == 0) ? 0 : s_w[wid - 1];
    const int excl = running + wb + incl - x;
    if (i < n) { off[i] = excl; cur[i] = excl; }
    const int tot = s_w[15];
    __syncthreads();
    running += tot;
  }
  if (tid == 0) off[n] = running;
}

// ---------------------------------------------------------------------------
// LDS-binning by coarse bucket (int LDS atomics only). Per 4096-edge tile:
// LDS hist -> LDS scan -> LDS reorder -> per-bucket global reservation ->
// contiguous-run writeout. Record = (dst_local<<17 | src, val_bits), 8B.
// ---------------------------------------------------------------------------
__global__ __launch_bounds__(256) void binning_kernel(
    const int* __restrict__ keys, const int* __restrict__ srcs,
    const float* __restrict__ vals, int* __restrict__ cb_cur,
    uint2* __restrict__ out, int nnz, int nb, int bshift, int bmask) {
  __shared__ int sh[NB_MAX];
  __shared__ int scnt[NB_MAX];
  __shared__ int sg[NB_MAX];
  __shared__ uint2 sbuf[TILE];
  __shared__ unsigned short sbk[TILE];
  __shared__ int s_w[8];

  const int tid = threadIdx.x, lane = tid & 63, wid = tid >> 6;
  const int tbase = blockIdx.x * TILE;
  const int total = min(TILE, nnz - tbase);

  for (int j = tid; j < nb; j += 256) sh[j] = 0;
  __syncthreads();

  int bk[16]; unsigned pk[16]; unsigned vv[16];
  #pragma unroll
  for (int k = 0; k < 16; ++k) {
    const int i = tbase + k * 256 + tid;
    if (i < nnz) {
      const int key = keys[i];
      const int b = key >> bshift;
      bk[k] = b;
      pk[k] = ((unsigned)(key & bmask) << 17) | (unsigned)srcs[i];
      vv[k] = __float_as_uint(vals[i]);
      atomicAdd(&sh[b], 1);
    } else {
      bk[k] = -1; pk[k] = 0; vv[k] = 0;
    }
  }
  __syncthreads();

  int carry = 0;
  for (int cb = 0; cb < nb; cb += 256) {
    const int idx = cb + tid;
    const int x = (idx < nb) ? sh[idx] : 0;
    int incl = x;
    #pragma unroll
    for (int d = 1; d < 64; d <<= 1) {
      int t = __shfl_up(incl, d);
      if (lane >= d) incl += t;
    }
    if (lane == 63) s_w[wid] = incl;
    __syncthreads();
    if (tid == 0) {
      int a = 0;
      #pragma unroll
      for (int w = 0; w < 4; ++w) { const int t = s_w[w]; s_w[w] = a; a += t; }
      s_w[4] = a;
    }
    __syncthreads();
    const int excl = carry + s_w[wid] + incl - x;
    if (idx < nb) { scnt[idx] = x; sh[idx] = excl; }
    carry += s_w[4];
    __syncthreads();
  }

  #pragma unroll
  for (int k = 0; k < 16; ++k) {
    if (bk[k] >= 0) {
      const int p = atomicAdd(&sh[bk[k]], 1);
      sbuf[p] = make_uint2(pk[k], vv[k]);
      sbk[p] = (unsigned short)bk[k];
    }
  }
  __syncthreads();

  for (int b = tid; b < nb; b += 256) {
    const int c = scnt[b];
    if (c > 0) sg[b] = atomicAdd(&cb_cur[b], c);
    scnt[b] = sh[b] - c;  // = excl[b]
  }
  __syncthreads();

  for (int p = tid; p < total; p += 256) {
    const int b = sbk[p];
    out[sg[b] + (p - scnt[b])] = sbuf[p];
  }
}

// ---------------------------------------------------------------------------
// Fine sort within each coarse bucket -> exact CSR. One block per bucket.
// Pass 1: LDS int histogram of <=64 local dests. Scan in wave 0. Emit global
// row offsets. Pass 2: scatter records into the bucket's contiguous global
// window (dense 8KB region -> write-amp ~1). No capacity limits.
// ---------------------------------------------------------------------------
__global__ __launch_bounds__(256) void fine_sort_kernel(
    const uint2* __restrict__ in, const int* __restrict__ cb_off,
    uint2* __restrict__ out, int* __restrict__ row_off, int bd, int ndst) {
  __shared__ int cnt[64];
  const int b = blockIdx.x, tid = threadIdx.x;
  const int beg = cb_off[b], end = cb_off[b + 1], n = end - beg;

  if (tid < bd) cnt[tid] = 0;
  __syncthreads();

  for (int i = tid; i < n; i += 256)
    atomicAdd(&cnt[in[beg + i].x >> 17], 1);
  __syncthreads();

  if (tid < 64) {
    const int x = (tid < bd) ? cnt[tid] : 0;
    int incl = x;
    #pragma unroll
    for (int d = 1; d < 64; d <<= 1) {
      int t = __shfl_up(incl, d);
      if (tid >= d) incl += t;
    }
    if (tid < bd) cnt[tid] = incl - x;  // exclusive offsets -> cursors
  }
  __syncthreads();

  const int base_row = b * bd;
  if (tid < bd && base_row + tid < ndst) row_off[base_row + tid] = beg + cnt[tid];
  if (b == 0 && tid == 0) row_off[ndst] = NNZ_EDGES;
  __syncthreads();

  for (int i = tid; i < n; i += 256) {
    const uint2 r = in[beg + i];
    const int dl = r.x >> 17;
    const int p = atomicAdd(&cnt[dl], 1);
    out[beg + p] = r;
  }
}

// ---------------------------------------------------------------------------
// CSR SpMM + fused ReLU. One wave per destination row; lane = feature.
// Register accumulation (NO atomics). Edge batch loaded coalesced (64/wave),
// broadcast by shfl; 4 independent bf16 gathers in flight per step.
// ---------------------------------------------------------------------------
__global__ __launch_bounds__(256) void spmm_csr_kernel(
    const uint2* __restrict__ edges, const int* __restrict__ row_off,
    const unsigned short* __restrict__ xw, float* __restrict__ out, int ndst) {
  const int wid = threadIdx.x >> 6, lane = threadIdx.x & 63;
  const int d = blockIdx.x * 4 + wid;
  if (d >= ndst) return;

  const int beg = row_off[d], end = row_off[d + 1];
  float acc = 0.f;

  for (int kb = beg; kb < end; kb += 64) {
    const int nbt = min(64, end - kb);
    uint2 rec = make_uint2(0u, 0u);
    if (lane < nbt) rec = edges[kb + lane];

    int j = 0;
    for (; j + 4 <= nbt; j += 4) {
      const int s0 = __shfl((int)rec.x, j)     & 0x1FFFF;
      const int s1 = __shfl((int)rec.x, j + 1) & 0x1FFFF;
      const int s2 = __shfl((int)rec.x, j + 2) & 0x1FFFF;
      const int s3 = __shfl((int)rec.x, j + 3) & 0x1FFFF;
      const float v0 = __uint_as_float((unsigned)__shfl((int)rec.y, j));
      const float v1 = __uint_as_float((unsigned)__shfl((int)rec.y, j + 1));
      const float v2 = __uint_as_float((unsigned)__shfl((int)rec.y, j + 2));
      const float v3 = __uint_as_float((unsigned)__shfl((int)rec.y, j + 3));
      const unsigned short h0 = xw[(size_t)s0 * DIM + lane];
      const unsigned short h1 = xw[(size_t)s1 * DIM + lane];
      const unsigned short h2 = xw[(size_t)s2 * DIM + lane];
      const unsigned short h3 = xw[(size_t)s3 * DIM + lane];
      acc = fmaf(v0, bf16_to_f32(h0), acc);
      acc = fmaf(v1, bf16_to_f32(h1), acc);
      acc = fmaf(v2, bf16_to_f32(h2), acc);
      acc = fmaf(v3, bf16_to_f32(h3), acc);
    }
    for (; j < nbt; ++j) {
      const int s = __shfl((int)rec.x, j) & 0x1FFFF;
      const float v = __uint_as_float((unsigned)__shfl((int)rec.y, j));
      acc = fmaf(v, bf16_to_f32(xw[(size_t)s * DIM + lane]), acc);
    }
  }
  out[(size_t)d * DIM + lane] = fmaxf(acc, 0.f);
}

extern "C" void kernel_launch(void* const* d_in, const int* in_sizes, int n_in,
                              void* d_out, int out_size, void* d_ws, size_t ws_size,
                              hipStream_t stream) {
  const float* user_x      = (const float*)d_in[0];
  const float* item_x      = (const float*)d_in[1];
  const float* user_weight = (const float*)d_in[2];
  const float* item_weight = (const float*)d_in[3];
  const int*   ui_rows     = (const int*)d_in[4];
  const int*   ui_cols     = (const int*)d_in[5];
  const float* ui_vals     = (const float*)d_in[6];

  float* out_user = (float*)d_out;
  float* out_item = (float*)d_out + (size_t)N_USERS * DIM;

  // ---- workspace layout --------------------------------------------------
  unsigned short* xw_user = (unsigned short*)d_ws;               // 6.4M bf16
  unsigned short* xw_item = xw_user + (size_t)N_USERS * DIM;     // 3.2M bf16
  uint2* binA = (uint2*)(xw_item + (size_t)N_ITEMS * DIM);       // coarse user / sorted item
  uint2* binB = binA + NNZ_EDGES;                                // coarse item
  uint2* binC = binB + NNZ_EDGES;                                // sorted user
  int*   urow_off = (int*)(binC + NNZ_EDGES);                    // N_USERS+1
  int*   irow_off = urow_off + (N_USERS + 1);                    // N_ITEMS+1
  int*   cbu_cnt  = irow_off + (N_ITEMS + 1);                    // NBU
  int*   cbi_cnt  = cbu_cnt + NBU;                               // NBI
  int*   cbu_off  = cbi_cnt + NBI;                               // NBU+1
  int*   cbi_off  = cbu_off + (NBU + 1);                         // NBI+1
  int*   cbu_cur  = cbi_off + (NBI + 1);                         // NBU
  int*   cbi_cur  = cbu_cur + NBU;                               // NBI
  // total ~58.3 MB

  // Dense projections (bf16 output for the gather phase).
  gemm64_bf16_kernel<<<(N_USERS + 15) / 16, 256, 0, stream>>>(user_x, user_weight, xw_user, N_USERS);
  gemm64_bf16_kernel<<<(N_ITEMS + 15) / 16, 256, 0, stream>>>(item_x, item_weight, xw_item, N_ITEMS);

  // Coarse bucket counts -> offsets/cursors.
  hipMemsetAsync(cbu_cnt, 0, (NBU + NBI) * sizeof(int), stream);
  bucket_hist_kernel<<<256, 256, 0, stream>>>(ui_rows, ui_cols, cbu_cnt, cbi_cnt, NNZ_EDGES);
  coarse_scan_kernel<<<2, 1024, 0, stream>>>(cbu_cnt, cbu_off, cbu_cur,
                                             cbi_cnt, cbi_off, cbi_cur);

  // Coarse binning (both directions).
  const int nblk = (NNZ_EDGES + TILE - 1) / TILE;
  binning_kernel<<<nblk, 256, 0, stream>>>(ui_rows, ui_cols, ui_vals, cbu_cur,
                                           binA, NNZ_EDGES, NBU, BSHIFT_U, BD_U - 1);
  binning_kernel<<<nblk, 256, 0, stream>>>(ui_cols, ui_rows, ui_vals, cbi_cur,
                                           binB, NNZ_EDGES, NBI, BSHIFT_I, BD_I - 1);

  // Fine sort -> exact CSR. (binA dead after first call; reused as item output.)
  fine_sort_kernel<<<NBU, 256, 0, stream>>>(binA, cbu_off, binC, urow_off, BD_U, N_USERS);
  fine_sort_kernel<<<NBI, 256, 0, stream>>>(binB, cbi_off, binA, irow_off, BD_I, N_ITEMS);

  // CSR SpMM + fused ReLU (register accumulation, no atomics).
  spmm_csr_kernel<<<(N_USERS + 3) / 4, 256, 0, stream>>>(binC, urow_off, xw_item, out_user, N_USERS);
  spmm_csr_kernel<<<(N_ITEMS + 3) / 4, 256, 0, stream>>>(binA, irow_off, xw_user, out_item, N_ITEMS);
}

// Round 6
// 237.767 us; speedup vs baseline: 6.8167x; 1.3826x over previous
//
#include <hip/hip_runtime.h>
#include <hip/hip_bf16.h>

#define N_USERS 100000
#define N_ITEMS 50000
#define NNZ_EDGES 1600000
#define DIM 64

#define BSHIFT_U 6
#define BD_U 64                              // user dests per coarse bucket
#define BSHIFT_I 5
#define BD_I 32                              // item dests per coarse bucket
#define NBU ((N_USERS + BD_U - 1) / BD_U)    // 1563
#define NBI ((N_ITEMS + BD_I - 1) / BD_I)    // 1563
#define NB_MAX 1563
#define TILE 4096                            // edges per binning tile

__device__ inline unsigned short f32_to_bf16(float f) {
  unsigned u = __float_as_uint(f);
  unsigned r = (u + 0x7FFFu + ((u >> 16) & 1u)) >> 16;  // RNE
  return (unsigned short)r;
}
__device__ inline float bf16_to_f32(unsigned short h) {
  return __uint_as_float((unsigned)h << 16);
}

// ---------------------------------------------------------------------------
// Dense GEMM: Y[nrows,64] = bf16(X @ W). 64-row tile per 256-thread block,
// 4x4 register blocking per thread. LDS: sXT[k][row] + sW[k][col]; inner
// loop = 2x ds_read_b128 -> 16 FMA (broadcast-friendly, <=2-way bank alias).
// ---------------------------------------------------------------------------
__global__ __launch_bounds__(256) void gemm64_bf16_kernel(
    const float* __restrict__ X, const float* __restrict__ W,
    unsigned short* __restrict__ Y, int nrows) {
  __shared__ float sXT[64][64];   // [k][row]
  __shared__ float sW[64][64];    // [k][col] — same layout as W itself
  const int tid = threadIdx.x;
  const int row_base = blockIdx.x * 64;

  // Stage W (4096 floats) coalesced, straight copy (already k-major).
  {
    const float4* Wv = (const float4*)W;
    float4* sWv = (float4*)&sW[0][0];
    #pragma unroll
    for (int i = 0; i < 4; ++i) sWv[tid + i * 256] = Wv[tid + i * 256];
  }
  // Stage X transposed: thread t -> row = t&63, k-window = (t>>6)*16.
  // Global: each 64B line of X read exactly once. LDS writes: 2-way alias (free).
  {
    const int r = tid & 63;
    const int k0 = (tid >> 6) * 16;
    const int grow = row_base + r;
    #pragma unroll
    for (int i = 0; i < 4; ++i) {
      float4 v = make_float4(0.f, 0.f, 0.f, 0.f);
      if (grow < nrows) v = ((const float4*)(X + (size_t)grow * DIM + k0))[i];
      sXT[k0 + i * 4 + 0][r] = v.x;
      sXT[k0 + i * 4 + 1][r] = v.y;
      sXT[k0 + i * 4 + 2][r] = v.z;
      sXT[k0 + i * 4 + 3][r] = v.w;
    }
  }
  __syncthreads();

  const int tx = tid & 15;   // cols tx*4 .. tx*4+3
  const int ty = tid >> 4;   // rows ty*4 .. ty*4+3
  float acc[4][4] = {{0.f}};

  #pragma unroll 8
  for (int k = 0; k < 64; ++k) {
    const float4 a = *(const float4*)&sXT[k][ty * 4];
    const float4 b = *(const float4*)&sW[k][tx * 4];
    acc[0][0] = fmaf(a.x, b.x, acc[0][0]);
    acc[0][1] = fmaf(a.x, b.y, acc[0][1]);
    acc[0][2] = fmaf(a.x, b.z, acc[0][2]);
    acc[0][3] = fmaf(a.x, b.w, acc[0][3]);
    acc[1][0] = fmaf(a.y, b.x, acc[1][0]);
    acc[1][1] = fmaf(a.y, b.y, acc[1][1]);
    acc[1][2] = fmaf(a.y, b.z, acc[1][2]);
    acc[1][3] = fmaf(a.y, b.w, acc[1][3]);
    acc[2][0] = fmaf(a.z, b.x, acc[2][0]);
    acc[2][1] = fmaf(a.z, b.y, acc[2][1]);
    acc[2][2] = fmaf(a.z, b.z, acc[2][2]);
    acc[2][3] = fmaf(a.z, b.w, acc[2][3]);
    acc[3][0] = fmaf(a.w, b.x, acc[3][0]);
    acc[3][1] = fmaf(a.w, b.y, acc[3][1]);
    acc[3][2] = fmaf(a.w, b.z, acc[3][2]);
    acc[3][3] = fmaf(a.w, b.w, acc[3][3]);
  }

  #pragma unroll
  for (int r = 0; r < 4; ++r) {
    const int grow = row_base + ty * 4 + r;
    if (grow < nrows) {
      ushort4 o;
      o.x = f32_to_bf16(acc[r][0]);
      o.y = f32_to_bf16(acc[r][1]);
      o.z = f32_to_bf16(acc[r][2]);
      o.w = f32_to_bf16(acc[r][3]);
      *(ushort4*)(Y + (size_t)grow * DIM + tx * 4) = o;
    }
  }
}

// ---------------------------------------------------------------------------
// Coarse bucket histogram, both directions (LDS int hist per block).
// ---------------------------------------------------------------------------
__global__ __launch_bounds__(256) void bucket_hist_kernel(
    const int* __restrict__ rows, const int* __restrict__ cols,
    int* __restrict__ ucnt, int* __restrict__ icnt, int nnz) {
  __shared__ int hu[NBU];
  __shared__ int hi_[NBI];
  for (int j = threadIdx.x; j < NBU; j += 256) hu[j] = 0;
  for (int j = threadIdx.x; j < NBI; j += 256) hi_[j] = 0;
  __syncthreads();
  for (int i = blockIdx.x * 256 + threadIdx.x; i < nnz; i += gridDim.x * 256) {
    atomicAdd(&hu[rows[i] >> BSHIFT_U], 1);
    atomicAdd(&hi_[cols[i] >> BSHIFT_I], 1);
  }
  __syncthreads();
  for (int j = threadIdx.x; j < NBU; j += 256) if (hu[j]) atomicAdd(&ucnt[j], hu[j]);
  for (int j = threadIdx.x; j < NBI; j += 256) if (hi_[j]) atomicAdd(&icnt[j], hi_[j]);
}

// ---------------------------------------------------------------------------
// Exclusive scan of bucket counts (n up to 1563, chunked by 1024).
// Block 0 = user, block 1 = item. Writes off[0..n], initializes cur = off.
// ---------------------------------------------------------------------------
__global__ __launch_bounds__(1024) void coarse_scan_kernel(
    int* __restrict__ ucnt, int* __restrict__ uoff, int* __restrict__ ucur,
    int* __restrict__ icnt, int* __restrict__ ioff, int* __restrict__ icur) {
  __shared__ int s_w[16];
  int *cnt, *off, *cur; int n;
  if (blockIdx.x == 0) { cnt = ucnt; off = uoff; cur = ucur; n = NBU; }
  else                 { cnt = icnt; off = ioff; cur = icur; n = NBI; }
  const int tid = threadIdx.x, lane = tid & 63, wid = tid >> 6;

  int running = 0;
  for (int base = 0; base < n; base += 1024) {
    const int i = base + tid;
    const int x = (i < n) ? cnt[i] : 0;
    int incl = x;
    #pragma unroll
    for (int d = 1; d < 64; d <<= 1) {
      int t = __shfl_up(incl, d);
      if (lane >= d) incl += t;
    }
    if (lane == 63) s_w[wid] = incl;
    __syncthreads();
    if (wid == 0) {
      int y = (lane < 16) ? s_w[lane] : 0;
      #pragma unroll
      for (int d = 1; d < 16; d <<= 1) {
        int t = __shfl_up(y, d);
        if (lane >= d) y += t;
      }
      if (lane < 16) s_w[lane] = y;
    }
    __syncthreads();
    const int wb = (wid == 0) ? 0 : s_w[wid - 1];
    const int excl = running + wb + incl - x;
    if (i < n) { off[i] = excl; cur[i] = excl; }
    const int tot = s_w[15];
    __syncthreads();
    running += tot;
  }
  if (tid == 0) off[n] = running;
}

// ---------------------------------------------------------------------------
// LDS-binning by coarse bucket (int LDS atomics only). Per 4096-edge tile:
// LDS hist -> LDS scan -> LDS reorder -> per-bucket global reservation ->
// contiguous-run writeout. Record = (dst_local<<17 | src, val_bits), 8B.
// ---------------------------------------------------------------------------
__global__ __launch_bounds__(256) void binning_kernel(
    const int* __restrict__ keys, const int* __restrict__ srcs,
    const float* __restrict__ vals, int* __restrict__ cb_cur,
    uint2* __restrict__ out, int nnz, int nb, int bshift, int bmask) {
  __shared__ int sh[NB_MAX];
  __shared__ int scnt[NB_MAX];
  __shared__ int sg[NB_MAX];
  __shared__ uint2 sbuf[TILE];
  __shared__ unsigned short sbk[TILE];
  __shared__ int s_w[8];

  const int tid = threadIdx.x, lane = tid & 63, wid = tid >> 6;
  const int tbase = blockIdx.x * TILE;
  const int total = min(TILE, nnz - tbase);

  for (int j = tid; j < nb; j += 256) sh[j] = 0;
  __syncthreads();

  int bk[16]; unsigned pk[16]; unsigned vv[16];
  #pragma unroll
  for (int k = 0; k < 16; ++k) {
    const int i = tbase + k * 256 + tid;
    if (i < nnz) {
      const int key = keys[i];
      const int b = key >> bshift;
      bk[k] = b;
      pk[k] = ((unsigned)(key & bmask) << 17) | (unsigned)srcs[i];
      vv[k] = __float_as_uint(vals[i]);
      atomicAdd(&sh[b], 1);
    } else {
      bk[k] = -1; pk[k] = 0; vv[k] = 0;
    }
  }
  __syncthreads();

  int carry = 0;
  for (int cb = 0; cb < nb; cb += 256) {
    const int idx = cb + tid;
    const int x = (idx < nb) ? sh[idx] : 0;
    int incl = x;
    #pragma unroll
    for (int d = 1; d < 64; d <<= 1) {
      int t = __shfl_up(incl, d);
      if (lane >= d) incl += t;
    }
    if (lane == 63) s_w[wid] = incl;
    __syncthreads();
    if (tid == 0) {
      int a = 0;
      #pragma unroll
      for (int w = 0; w < 4; ++w) { const int t = s_w[w]; s_w[w] = a; a += t; }
      s_w[4] = a;
    }
    __syncthreads();
    const int excl = carry + s_w[wid] + incl - x;
    if (idx < nb) { scnt[idx] = x; sh[idx] = excl; }
    carry += s_w[4];
    __syncthreads();
  }

  #pragma unroll
  for (int k = 0; k < 16; ++k) {
    if (bk[k] >= 0) {
      const int p = atomicAdd(&sh[bk[k]], 1);
      sbuf[p] = make_uint2(pk[k], vv[k]);
      sbk[p] = (unsigned short)bk[k];
    }
  }
  __syncthreads();

  for (int b = tid; b < nb; b += 256) {
    const int c = scnt[b];
    if (c > 0) sg[b] = atomicAdd(&cb_cur[b], c);
    scnt[b] = sh[b] - c;  // = excl[b]
  }
  __syncthreads();

  for (int p = tid; p < total; p += 256) {
    const int b = sbk[p];
    out[sg[b] + (p - scnt[b])] = sbuf[p];
  }
}

// ---------------------------------------------------------------------------
// Fine sort within each coarse bucket -> exact CSR. One block per bucket.
// ---------------------------------------------------------------------------
__global__ __launch_bounds__(256) void fine_sort_kernel(
    const uint2* __restrict__ in, const int* __restrict__ cb_off,
    uint2* __restrict__ out, int* __restrict__ row_off, int bd, int ndst) {
  __shared__ int cnt[64];
  const int b = blockIdx.x, tid = threadIdx.x;
  const int beg = cb_off[b], end = cb_off[b + 1], n = end - beg;

  if (tid < bd) cnt[tid] = 0;
  __syncthreads();

  for (int i = tid; i < n; i += 256)
    atomicAdd(&cnt[in[beg + i].x >> 17], 1);
  __syncthreads();

  if (tid < 64) {
    const int x = (tid < bd) ? cnt[tid] : 0;
    int incl = x;
    #pragma unroll
    for (int d = 1; d < 64; d <<= 1) {
      int t = __shfl_up(incl, d);
      if (tid >= d) incl += t;
    }
    if (tid < bd) cnt[tid] = incl - x;  // exclusive offsets -> cursors
  }
  __syncthreads();

  const int base_row = b * bd;
  if (tid < bd && base_row + tid < ndst) row_off[base_row + tid] = beg + cnt[tid];
  if (b == 0 && tid == 0) row_off[ndst] = NNZ_EDGES;
  __syncthreads();

  for (int i = tid; i < n; i += 256) {
    const uint2 r = in[beg + i];
    const int dl = r.x >> 17;
    const int p = atomicAdd(&cnt[dl], 1);
    out[beg + p] = r;
  }
}

// ---------------------------------------------------------------------------
// CSR SpMM + fused ReLU. One wave per destination row; lane = feature.
// Register accumulation, shfl-broadcast edges, 4 gathers in flight.
// ---------------------------------------------------------------------------
__global__ __launch_bounds__(256) void spmm_csr_kernel(
    const uint2* __restrict__ edges, const int* __restrict__ row_off,
    const unsigned short* __restrict__ xw, float* __restrict__ out, int ndst) {
  const int wid = threadIdx.x >> 6, lane = threadIdx.x & 63;
  const int d = blockIdx.x * 4 + wid;
  if (d >= ndst) return;

  const int beg = row_off[d], end = row_off[d + 1];
  float acc = 0.f;

  for (int kb = beg; kb < end; kb += 64) {
    const int nbt = min(64, end - kb);
    uint2 rec = make_uint2(0u, 0u);
    if (lane < nbt) rec = edges[kb + lane];

    int j = 0;
    for (; j + 4 <= nbt; j += 4) {
      const int s0 = __shfl((int)rec.x, j)     & 0x1FFFF;
      const int s1 = __shfl((int)rec.x, j + 1) & 0x1FFFF;
      const int s2 = __shfl((int)rec.x, j + 2) & 0x1FFFF;
      const int s3 = __shfl((int)rec.x, j + 3) & 0x1FFFF;
      const float v0 = __uint_as_float((unsigned)__shfl((int)rec.y, j));
      const float v1 = __uint_as_float((unsigned)__shfl((int)rec.y, j + 1));
      const float v2 = __uint_as_float((unsigned)__shfl((int)rec.y, j + 2));
      const float v3 = __uint_as_float((unsigned)__shfl((int)rec.y, j + 3));
      const unsigned short h0 = xw[(size_t)s0 * DIM + lane];
      const unsigned short h1 = xw[(size_t)s1 * DIM + lane];
      const unsigned short h2 = xw[(size_t)s2 * DIM + lane];
      const unsigned short h3 = xw[(size_t)s3 * DIM + lane];
      acc = fmaf(v0, bf16_to_f32(h0), acc);
      acc = fmaf(v1, bf16_to_f32(h1), acc);
      acc = fmaf(v2, bf16_to_f32(h2), acc);
      acc = fmaf(v3, bf16_to_f32(h3), acc);
    }
    for (; j < nbt; ++j) {
      const int s = __shfl((int)rec.x, j) & 0x1FFFF;
      const float v = __uint_as_float((unsigned)__shfl((int)rec.y, j));
      acc = fmaf(v, bf16_to_f32(xw[(size_t)s * DIM + lane]), acc);
    }
  }
  out[(size_t)d * DIM + lane] = fmaxf(acc, 0.f);
}

extern "C" void kernel_launch(void* const* d_in, const int* in_sizes, int n_in,
                              void* d_out, int out_size, void* d_ws, size_t ws_size,
                              hipStream_t stream) {
  const float* user_x      = (const float*)d_in[0];
  const float* item_x      = (const float*)d_in[1];
  const float* user_weight = (const float*)d_in[2];
  const float* item_weight = (const float*)d_in[3];
  const int*   ui_rows     = (const int*)d_in[4];
  const int*   ui_cols     = (const int*)d_in[5];
  const float* ui_vals     = (const float*)d_in[6];

  float* out_user = (float*)d_out;
  float* out_item = (float*)d_out + (size_t)N_USERS * DIM;

  // ---- workspace layout --------------------------------------------------
  unsigned short* xw_user = (unsigned short*)d_ws;               // 6.4M bf16
  unsigned short* xw_item = xw_user + (size_t)N_USERS * DIM;     // 3.2M bf16
  uint2* binA = (uint2*)(xw_item + (size_t)N_ITEMS * DIM);       // coarse user / sorted item
  uint2* binB = binA + NNZ_EDGES;                                // coarse item
  uint2* binC = binB + NNZ_EDGES;                                // sorted user
  int*   urow_off = (int*)(binC + NNZ_EDGES);                    // N_USERS+1
  int*   irow_off = urow_off + (N_USERS + 1);                    // N_ITEMS+1
  int*   cbu_cnt  = irow_off + (N_ITEMS + 1);                    // NBU
  int*   cbi_cnt  = cbu_cnt + NBU;                               // NBI
  int*   cbu_off  = cbi_cnt + NBI;                               // NBU+1
  int*   cbi_off  = cbu_off + (NBU + 1);                         // NBI+1
  int*   cbu_cur  = cbi_off + (NBI + 1);                         // NBU
  int*   cbi_cur  = cbu_cur + NBU;                               // NBI
  // total ~58.3 MB

  // Dense projections (bf16 output for the gather phase).
  gemm64_bf16_kernel<<<(N_USERS + 63) / 64, 256, 0, stream>>>(user_x, user_weight, xw_user, N_USERS);
  gemm64_bf16_kernel<<<(N_ITEMS + 63) / 64, 256, 0, stream>>>(item_x, item_weight, xw_item, N_ITEMS);

  // Coarse bucket counts -> offsets/cursors.
  hipMemsetAsync(cbu_cnt, 0, (NBU + NBI) * sizeof(int), stream);
  bucket_hist_kernel<<<256, 256, 0, stream>>>(ui_rows, ui_cols, cbu_cnt, cbi_cnt, NNZ_EDGES);
  coarse_scan_kernel<<<2, 1024, 0, stream>>>(cbu_cnt, cbu_off, cbu_cur,
                                             cbi_cnt, cbi_off, cbi_cur);

  // Coarse binning (both directions).
  const int nblk = (NNZ_EDGES + TILE - 1) / TILE;
  binning_kernel<<<nblk, 256, 0, stream>>>(ui_rows, ui_cols, ui_vals, cbu_cur,
                                           binA, NNZ_EDGES, NBU, BSHIFT_U, BD_U - 1);
  binning_kernel<<<nblk, 256, 0, stream>>>(ui_cols, ui_rows, ui_vals, cbi_cur,
                                           binB, NNZ_EDGES, NBI, BSHIFT_I, BD_I - 1);

  // Fine sort -> exact CSR. (binA dead after first call; reused as item output.)
  fine_sort_kernel<<<NBU, 256, 0, stream>>>(binA, cbu_off, binC, urow_off, BD_U, N_USERS);
  fine_sort_kernel<<<NBI, 256, 0, stream>>>(binB, cbi_off, binA, irow_off, BD_I, N_ITEMS);

  // CSR SpMM + fused ReLU (register accumulation, no atomics).
  spmm_csr_kernel<<<(N_USERS + 3) / 4, 256, 0, stream>>>(binC, urow_off, xw_item, out_user, N_USERS);
  spmm_csr_kernel<<<(N_ITEMS + 3) / 4, 256, 0, stream>>>(binA, irow_off, xw_user, out_item, N_ITEMS);
}